// Round 5
// baseline (150.181 us; speedup 1.0000x reference)
//
#include <hip/hip_runtime.h>

// Kernel 1: per-block partial sums of squared differences.
//
// Round-5 restructure: the blocked layout (each block owns a 32 KB window,
// threads stride 4 KB inside it) ran at 3.2 TB/s effective and — key clue —
// took the SAME 43 us whether the data came from HBM (65 MB fetch) or was
// fully L3-resident (65 KB fetch). A BW/latency-bound kernel would speed up
// on L3 hits; this didn't => the cost is in the access pattern, common to
// both paths (scattered 4-KB-strided frontier, p/t aliasing to the same
// channel residues). The proven-fast kernels on this chip (m13 copy
// 6.29 TB/s, m146 RMSNorm 4.89 TB/s) use a chip-wide sequential grid-stride
// sweep: dense contiguous frontier, consecutive per-thread iterations ~8 MB
// apart. This kernel replicates that skeleton exactly.
//
// 2047 blocks x 256 threads, stride = 2047*256 = 524,032 float4s/iter,
// 8 iterations exactly: 524,032 * 8 = 4,192,256 = B*S*2/4. No bounds
// checks, no divergence (n4 is passed at runtime so the loop stays rolled,
// like the copy bench).
__global__ __launch_bounds__(256, 4) void ssd_partials(const float4* __restrict__ p,
                                                       const float4* __restrict__ t,
                                                       float* __restrict__ ws,
                                                       int n4) {
    const int tid = threadIdx.x;
    const int stride = gridDim.x * 256;   // runtime => loop stays rolled
    int i = blockIdx.x * 256 + tid;

    float acc0 = 0.f, acc1 = 0.f, acc2 = 0.f, acc3 = 0.f;
    for (; i < n4; i += stride) {
        float4 a = p[i];
        float4 b = t[i];
        float dx = a.x - b.x; acc0 += dx * dx;
        float dy = a.y - b.y; acc1 += dy * dy;
        float dz = a.z - b.z; acc2 += dz * dz;
        float dw = a.w - b.w; acc3 += dw * dw;
    }
    float acc = (acc0 + acc1) + (acc2 + acc3);

    // wave-64 reduce
    #pragma unroll
    for (int off = 32; off > 0; off >>= 1)
        acc += __shfl_down(acc, off, 64);

    __shared__ float wave_sums[4];
    const int lane = tid & 63;
    const int wave = tid >> 6;
    if (lane == 0) wave_sums[wave] = acc;
    __syncthreads();

    if (tid == 0)
        ws[blockIdx.x] = (wave_sums[0] + wave_sums[1]) + (wave_sums[2] + wave_sums[3]);
}

// Kernel 2: reduce 2047 partials -> out[0] = sum * scale.
// Single block of 256; every ws slot read was written by kernel 1.
// Deterministic read order => bit-exact across runs.
__global__ __launch_bounds__(256) void ssd_finalize(const float* __restrict__ ws,
                                                    float* __restrict__ out,
                                                    float scale) {
    const int tid = threadIdx.x;
    float acc = 0.f;
    #pragma unroll
    for (int k = 0; k < 8; ++k) {
        int idx = tid + k * 256;
        if (idx < 2047) acc += ws[idx];
    }

    #pragma unroll
    for (int off = 32; off > 0; off >>= 1)
        acc += __shfl_down(acc, off, 64);

    __shared__ float wave_sums[4];
    const int lane = tid & 63;
    const int wave = tid >> 6;
    if (lane == 0) wave_sums[wave] = acc;
    __syncthreads();

    if (tid == 0)
        out[0] = ((wave_sums[0] + wave_sums[1]) + (wave_sums[2] + wave_sums[3])) * scale;
}

extern "C" void kernel_launch(void* const* d_in, const int* in_sizes, int n_in,
                              void* d_out, int out_size, void* d_ws, size_t ws_size,
                              hipStream_t stream) {
    const float* pred = (const float*)d_in[0];
    const float* targ = (const float*)d_in[1];
    float* out = (float*)d_out;
    float* ws = (float*)d_ws;  // needs 2047 floats = 8188 B

    const int B = 4096;
    const int S = 2047;  // 2*d+1 with d=1023 — slice covers the whole tensor
    const float scale = 1.0f / ((float)S * (float)B);
    const int n4 = B * S * 2 / 4;  // 4,192,256 float4 pairs = 2047*256*8 exactly

    ssd_partials<<<2047, 256, 0, stream>>>((const float4*)pred,
                                           (const float4*)targ, ws, n4);
    ssd_finalize<<<1, 256, 0, stream>>>(ws, out, scale);
}

// Round 6
// 144.213 us; speedup vs baseline: 1.0414x; 1.0414x over previous
//
#include <hip/hip_runtime.h>

// Clang ext_vector float4 — required for __builtin_nontemporal_load
// (the HIP float4 struct is not a clang vector type). No inline asm
// anywhere in this file (the round-1/2 build failures correlated with the
// 16-operand asm statement, not with ext_vector itself).
typedef float f4 __attribute__((ext_vector_type(4)));

// Kernel 1: per-block partial sums of squared differences.
//
// History: blocked layout (R0-R4) and chip-wide sweep (R5) both sit at
// 3.15 TB/s effective read (134 MB / 42.5 us) regardless of pipeline depth
// (VGPR 12 vs 32), scheduling directives, or fences. That equals the READ
// component of the m13 copy ceiling (6.29 TB/s traffic = 3.15r + 3.15w):
// consistent with a chip-wide read-supply cap (per-CU outstanding-line
// MSHRs x loaded latency), which wave-level restructuring cannot move.
//
// This round tests the one remaining cache-path mechanism: FETCH_SIZE shows
// exactly one tensor's worth (65.5 MB) coming from HBM per dispatch — the
// other half is L3 hits. If the L3-hit/mixed path is the slow component,
// nontemporal (no-allocate, LRU-bypass) loads change it; if this is null,
// we are at the platform read roofline.
__global__ __launch_bounds__(256, 4) void ssd_partials(const f4* __restrict__ p,
                                                       const f4* __restrict__ t,
                                                       float* __restrict__ ws,
                                                       int n4) {
    const int tid = threadIdx.x;
    const int stride = gridDim.x * 256;   // runtime => loop stays rolled
    int i = blockIdx.x * 256 + tid;

    float acc0 = 0.f, acc1 = 0.f, acc2 = 0.f, acc3 = 0.f;
    for (; i < n4; i += stride) {
        f4 a = __builtin_nontemporal_load(p + i);
        f4 b = __builtin_nontemporal_load(t + i);
        float dx = a.x - b.x; acc0 += dx * dx;
        float dy = a.y - b.y; acc1 += dy * dy;
        float dz = a.z - b.z; acc2 += dz * dz;
        float dw = a.w - b.w; acc3 += dw * dw;
    }
    float acc = (acc0 + acc1) + (acc2 + acc3);

    // wave-64 reduce
    #pragma unroll
    for (int off = 32; off > 0; off >>= 1)
        acc += __shfl_down(acc, off, 64);

    __shared__ float wave_sums[4];
    const int lane = tid & 63;
    const int wave = tid >> 6;
    if (lane == 0) wave_sums[wave] = acc;
    __syncthreads();

    if (tid == 0)
        ws[blockIdx.x] = (wave_sums[0] + wave_sums[1]) + (wave_sums[2] + wave_sums[3]);
}

// Kernel 2: reduce 2047 partials -> out[0] = sum * scale.
// Single block of 256; every ws slot read was written by kernel 1.
// Deterministic read order => bit-exact across runs.
__global__ __launch_bounds__(256) void ssd_finalize(const float* __restrict__ ws,
                                                    float* __restrict__ out,
                                                    float scale) {
    const int tid = threadIdx.x;
    float acc = 0.f;
    #pragma unroll
    for (int k = 0; k < 8; ++k) {
        int idx = tid + k * 256;
        if (idx < 2047) acc += ws[idx];
    }

    #pragma unroll
    for (int off = 32; off > 0; off >>= 1)
        acc += __shfl_down(acc, off, 64);

    __shared__ float wave_sums[4];
    const int lane = tid & 63;
    const int wave = tid >> 6;
    if (lane == 0) wave_sums[wave] = acc;
    __syncthreads();

    if (tid == 0)
        out[0] = ((wave_sums[0] + wave_sums[1]) + (wave_sums[2] + wave_sums[3])) * scale;
}

extern "C" void kernel_launch(void* const* d_in, const int* in_sizes, int n_in,
                              void* d_out, int out_size, void* d_ws, size_t ws_size,
                              hipStream_t stream) {
    const float* pred = (const float*)d_in[0];
    const float* targ = (const float*)d_in[1];
    float* out = (float*)d_out;
    float* ws = (float*)d_ws;  // needs 2047 floats = 8188 B

    const int B = 4096;
    const int S = 2047;  // 2*d+1 with d=1023 — slice covers the whole tensor
    const float scale = 1.0f / ((float)S * (float)B);
    const int n4 = B * S * 2 / 4;  // 4,192,256 float4 pairs = 2047*256*8 exactly

    ssd_partials<<<2047, 256, 0, stream>>>((const f4*)pred,
                                           (const f4*)targ, ws, n4);
    ssd_finalize<<<1, 256, 0, stream>>>(ws, out, scale);
}